// Round 1
// baseline (1083.420 us; speedup 1.0000x reference)
//
#include <hip/hip_runtime.h>
#include <hip/hip_bf16.h>

#define INV_SQRT2 0.7071067811865475f

// Transpose W_nn and W_res (torch [out,in] row-major) into k-major layout in ws.
__global__ __launch_bounds__(256) void transpose_w_kernel(
    const float* __restrict__ W_nn, const float* __restrict__ W_res,
    float* __restrict__ WT) {
  int idx = blockIdx.x * 256 + threadIdx.x;
  if (idx < 128 * 128) {
    int o = idx >> 7, k = idx & 127;
    WT[k * 128 + o] = W_nn[idx];
    WT[128 * 128 + k * 128 + o] = W_res[idx];
  }
}

// Per-edge: ea = W_edge @ attr ; msg = relu(x[src] + ea) ; atomic-add into aggr[dst].
// Block: 256 threads, tile of 32 edges. Thread = (er = tid>>5 -> 4 edges, og = tid&31 -> 4 outputs).
__global__ __launch_bounds__(256) void edge_kernel(
    const float* __restrict__ x, const int* __restrict__ ei,
    const float* __restrict__ edge_attr, const float* __restrict__ W_edge,
    float* aggr, int E) {
  __shared__ float Wl[64 * 128];   // k-major: Wl[k][o]
  __shared__ float Al[32 * 64];    // attr tile [e][k]
  const int tid = threadIdx.x;
  // stage W_edge transposed (once per block)
  for (int idx = tid; idx < 128 * 64; idx += 256) {
    int o = idx >> 6, k = idx & 63;
    Wl[k * 128 + o] = W_edge[idx];
  }
  const int og = tid & 31;
  const int er = tid >> 5;
  const int ntiles = (E + 31) >> 5;
  for (int tile = blockIdx.x; tile < ntiles; tile += gridDim.x) {
    __syncthreads();  // protects Al reuse and (first iter) W staging
    {
      const float* src_ptr = edge_attr + (size_t)tile * 32 * 64;
      const int limit = E * 64 - tile * 32 * 64;
      for (int idx = tid; idx < 2048; idx += 256)
        Al[idx] = (idx < limit) ? src_ptr[idx] : 0.f;
    }
    __syncthreads();
    float acc[4][4] = {};
    #pragma unroll 4
    for (int k = 0; k < 64; ++k) {
      const float4 w = *(const float4*)&Wl[k * 128 + og * 4];
      #pragma unroll
      for (int j = 0; j < 4; ++j) {
        const float a = Al[(er * 4 + j) * 64 + k];
        acc[j][0] = fmaf(a, w.x, acc[j][0]);
        acc[j][1] = fmaf(a, w.y, acc[j][1]);
        acc[j][2] = fmaf(a, w.z, acc[j][2]);
        acc[j][3] = fmaf(a, w.w, acc[j][3]);
      }
    }
    #pragma unroll
    for (int j = 0; j < 4; ++j) {
      const int e = tile * 32 + er * 4 + j;
      if (e < E) {
        const int s = ei[e];
        const int d = ei[E + e];
        const float4 xv = *(const float4*)&x[(size_t)s * 128 + og * 4];
        float* ap = aggr + (size_t)d * 128 + og * 4;
        atomicAdd(ap + 0, fmaxf(xv.x + acc[j][0], 0.f));
        atomicAdd(ap + 1, fmaxf(xv.y + acc[j][1], 0.f));
        atomicAdd(ap + 2, fmaxf(xv.z + acc[j][2], 0.f));
        atomicAdd(ap + 3, fmaxf(xv.w + acc[j][3], 0.f));
      }
    }
  }
}

// Per-node: u = (1+eps)*x + aggr ; out = (relu(u@WnnT + b) + x@WresT) / sqrt2.
// aggr is read from `io` (= d_out) and overwritten in place with the result.
__global__ __launch_bounds__(256) void node_kernel(
    const float* __restrict__ x, const float* __restrict__ WT,
    const float* __restrict__ b_nn, float* io, int N) {
  __shared__ float Ul[16 * 128];
  __shared__ float Xl[16 * 128];
  const int tid = threadIdx.x;
  const int og = tid & 31;
  const int nr = tid >> 5;
  const float* WnnT = WT;
  const float* WresT = WT + 128 * 128;
  const int ntiles = (N + 15) >> 4;
  for (int tile = blockIdx.x; tile < ntiles; tile += gridDim.x) {
    __syncthreads();
    {
      const size_t base = (size_t)tile * 16 * 128;
      const int limit = N * 128 - (int)base;
      for (int idx = tid; idx < 2048; idx += 256) {
        const float xv = (idx < limit) ? x[base + idx] : 0.f;
        const float av = (idx < limit) ? io[base + idx] : 0.f;
        Xl[idx] = xv;
        Ul[idx] = fmaf(1.00001f, xv, av);
      }
    }
    __syncthreads();
    float accn[2][4] = {}, accr[2][4] = {};
    #pragma unroll 4
    for (int k = 0; k < 128; ++k) {
      const float4 wn = *(const float4*)&WnnT[k * 128 + og * 4];
      const float4 wr = *(const float4*)&WresT[k * 128 + og * 4];
      #pragma unroll
      for (int j = 0; j < 2; ++j) {
        const float u = Ul[(nr * 2 + j) * 128 + k];
        const float xx = Xl[(nr * 2 + j) * 128 + k];
        accn[j][0] = fmaf(u, wn.x, accn[j][0]);
        accn[j][1] = fmaf(u, wn.y, accn[j][1]);
        accn[j][2] = fmaf(u, wn.z, accn[j][2]);
        accn[j][3] = fmaf(u, wn.w, accn[j][3]);
        accr[j][0] = fmaf(xx, wr.x, accr[j][0]);
        accr[j][1] = fmaf(xx, wr.y, accr[j][1]);
        accr[j][2] = fmaf(xx, wr.z, accr[j][2]);
        accr[j][3] = fmaf(xx, wr.w, accr[j][3]);
      }
    }
    const float4 b = *(const float4*)&b_nn[og * 4];
    #pragma unroll
    for (int j = 0; j < 2; ++j) {
      const int n = tile * 16 + nr * 2 + j;
      if (n < N) {
        float4 o4;
        o4.x = (fmaxf(accn[j][0] + b.x, 0.f) + accr[j][0]) * INV_SQRT2;
        o4.y = (fmaxf(accn[j][1] + b.y, 0.f) + accr[j][1]) * INV_SQRT2;
        o4.z = (fmaxf(accn[j][2] + b.z, 0.f) + accr[j][2]) * INV_SQRT2;
        o4.w = (fmaxf(accn[j][3] + b.w, 0.f) + accr[j][3]) * INV_SQRT2;
        *(float4*)&io[(size_t)n * 128 + og * 4] = o4;
      }
    }
  }
}

extern "C" void kernel_launch(void* const* d_in, const int* in_sizes, int n_in,
                              void* d_out, int out_size, void* d_ws, size_t ws_size,
                              hipStream_t stream) {
  const float* x      = (const float*)d_in[0];
  const int*   ei     = (const int*)d_in[1];
  const float* ea     = (const float*)d_in[2];
  const float* W_edge = (const float*)d_in[3];
  const float* W_nn   = (const float*)d_in[4];
  const float* b_nn   = (const float*)d_in[5];
  const float* W_res  = (const float*)d_in[6];
  float* out = (float*)d_out;
  float* WT  = (float*)d_ws;
  const int N = in_sizes[0] / 128;
  const int E = in_sizes[2] / 64;

  // aggr accumulates in d_out: zero it first (graph-capture-legal).
  hipMemsetAsync(d_out, 0, (size_t)N * 128 * sizeof(float), stream);
  transpose_w_kernel<<<(128 * 128 + 255) / 256, 256, 0, stream>>>(W_nn, W_res, WT);
  const int etiles = (E + 31) / 32;
  edge_kernel<<<(etiles < 4096 ? etiles : 4096), 256, 0, stream>>>(x, ei, ea, W_edge, out, E);
  const int ntiles = (N + 15) / 16;
  node_kernel<<<(ntiles < 2048 ? ntiles : 2048), 256, 0, stream>>>(x, WT, b_nn, out, N);
}

// Round 2
// 606.713 us; speedup vs baseline: 1.7857x; 1.7857x over previous
//
#include <hip/hip_runtime.h>
#include <hip/hip_bf16.h>

#define INV_SQRT2 0.7071067811865475f

static __device__ __forceinline__ unsigned short f2bf(float f) {
  __hip_bfloat16 h = __float2bfloat16(f);
  return *(unsigned short*)&h;
}

// ---------- weight transpose (k-major) ----------
__global__ __launch_bounds__(256) void transpose_w_kernel(
    const float* __restrict__ W_nn, const float* __restrict__ W_res,
    float* __restrict__ WT) {
  int idx = blockIdx.x * 256 + threadIdx.x;
  if (idx < 128 * 128) {
    int o = idx >> 7, k = idx & 127;
    WT[k * 128 + o] = W_nn[idx];
    WT[128 * 128 + k * 128 + o] = W_res[idx];
  }
}

// ---------- CSR build: histogram / scan / scatter ----------
__global__ __launch_bounds__(256) void hist_kernel(const int* __restrict__ ei,
                                                   int* cnt, int E) {
  int e = blockIdx.x * 256 + threadIdx.x;
  if (e < E) atomicAdd(&cnt[ei[E + e]], 1);
}

__global__ __launch_bounds__(256) void scan1_kernel(const int* __restrict__ cnt,
                                                    int* off, int* bsum, int N) {
  __shared__ int s[256];
  const int tid = threadIdx.x;
  const int gid = blockIdx.x * 256 + tid;
  const int v = (gid < N) ? cnt[gid] : 0;
  s[tid] = v;
  for (int o = 1; o < 256; o <<= 1) {
    __syncthreads();
    int t = (tid >= o) ? s[tid - o] : 0;
    __syncthreads();
    s[tid] += t;
  }
  if (gid < N) off[gid] = s[tid] - v;       // exclusive within block
  if (tid == 255) bsum[blockIdx.x] = s[255];
}

__global__ __launch_bounds__(512) void scan2_kernel(int* bsum, int nb) {
  __shared__ int s[512];
  const int tid = threadIdx.x;
  const int v = (tid < nb) ? bsum[tid] : 0;
  s[tid] = v;
  for (int o = 1; o < 512; o <<= 1) {
    __syncthreads();
    int t = (tid >= o) ? s[tid - o] : 0;
    __syncthreads();
    s[tid] += t;
  }
  if (tid < nb) bsum[tid] = s[tid] - v;     // exclusive block offsets
}

__global__ __launch_bounds__(256) void scan3_kernel(int* off, int* cur,
                                                    const int* __restrict__ bsum,
                                                    int N) {
  int gid = blockIdx.x * 256 + threadIdx.x;
  if (gid < N) {
    int v = off[gid] + bsum[blockIdx.x];
    off[gid] = v;
    cur[gid] = v;
  }
}

__global__ __launch_bounds__(256) void scatter_kernel(const int* __restrict__ ei,
                                                      int* cur, int* order, int E) {
  int e = blockIdx.x * 256 + threadIdx.x;
  if (e < E) {
    int p = atomicAdd(&cur[ei[E + e]], 1);
    order[p] = e;
  }
}

// ---------- phase 2a: per-edge message, written (no atomics) as bf16 ----------
// msg[e][:] = relu(x[src[e]] + W_edge @ attr[e])
__global__ __launch_bounds__(256) void msg_kernel(
    const float* __restrict__ x, const int* __restrict__ ei,
    const float* __restrict__ edge_attr, const float* __restrict__ W_edge,
    unsigned short* __restrict__ msg, int E) {
  __shared__ float Wl[64 * 128];   // k-major: Wl[k][o]
  __shared__ float Al[32 * 64];    // attr tile [e][k]
  const int tid = threadIdx.x;
  for (int idx = tid; idx < 128 * 64; idx += 256) {
    int o = idx >> 6, k = idx & 63;
    Wl[k * 128 + o] = W_edge[idx];
  }
  const int og = tid & 31;
  const int er = tid >> 5;
  const int ntiles = (E + 31) >> 5;
  for (int tile = blockIdx.x; tile < ntiles; tile += gridDim.x) {
    __syncthreads();
    {
      const float* src_ptr = edge_attr + (size_t)tile * 32 * 64;
      const int limit = E * 64 - tile * 32 * 64;
      for (int idx = tid; idx < 2048; idx += 256)
        Al[idx] = (idx < limit) ? src_ptr[idx] : 0.f;
    }
    __syncthreads();
    float acc[4][4] = {};
    #pragma unroll 4
    for (int k = 0; k < 64; ++k) {
      const float4 w = *(const float4*)&Wl[k * 128 + og * 4];
      #pragma unroll
      for (int j = 0; j < 4; ++j) {
        const float a = Al[(er * 4 + j) * 64 + k];
        acc[j][0] = fmaf(a, w.x, acc[j][0]);
        acc[j][1] = fmaf(a, w.y, acc[j][1]);
        acc[j][2] = fmaf(a, w.z, acc[j][2]);
        acc[j][3] = fmaf(a, w.w, acc[j][3]);
      }
    }
    #pragma unroll
    for (int j = 0; j < 4; ++j) {
      const int e = tile * 32 + er * 4 + j;
      if (e < E) {
        const int s = ei[e];
        const float4 xv = *(const float4*)&x[(size_t)s * 128 + og * 4];
        ushort4 pk;
        pk.x = f2bf(fmaxf(xv.x + acc[j][0], 0.f));
        pk.y = f2bf(fmaxf(xv.y + acc[j][1], 0.f));
        pk.z = f2bf(fmaxf(xv.z + acc[j][2], 0.f));
        pk.w = f2bf(fmaxf(xv.w + acc[j][3], 0.f));
        *(ushort4*)&msg[(size_t)e * 128 + og * 4] = pk;
      }
    }
  }
}

// ---------- phase 2b: CSR gather-sum + fused node GEMMs ----------
__global__ __launch_bounds__(256) void node_gather_kernel(
    const float* __restrict__ x, const float* __restrict__ WT,
    const float* __restrict__ b_nn, const int* __restrict__ off,
    const int* __restrict__ cnt, const int* __restrict__ order,
    const unsigned short* __restrict__ msg, float* __restrict__ out, int N) {
  __shared__ float Ul[16 * 128];
  __shared__ float Xl[16 * 128];
  const int tid = threadIdx.x;
  const int k = tid & 127;       // channel for the staging phase
  const int half = tid >> 7;     // 0/1: which node of the pair
  const int og = tid & 31;
  const int nr = tid >> 5;
  const float* WnnT = WT;
  const float* WresT = WT + 128 * 128;
  const int ntiles = (N + 15) >> 4;
  for (int tile = blockIdx.x; tile < ntiles; tile += gridDim.x) {
    __syncthreads();
    for (int j = half; j < 16; j += 2) {
      const int n = tile * 16 + j;
      float xv = 0.f, sum = 0.f;
      if (n < N) {
        xv = x[(size_t)n * 128 + k];
        const int o = off[n];
        const int c = cnt[n];
        for (int t = 0; t < c; ++t) {
          const int e = order[o + t];
          unsigned short u = msg[(size_t)e * 128 + k];
          unsigned int bits = ((unsigned int)u) << 16;
          sum += *(float*)&bits;
        }
      }
      Xl[j * 128 + k] = xv;
      Ul[j * 128 + k] = fmaf(1.00001f, xv, sum);
    }
    __syncthreads();
    float accn[2][4] = {}, accr[2][4] = {};
    #pragma unroll 4
    for (int kk = 0; kk < 128; ++kk) {
      const float4 wn = *(const float4*)&WnnT[kk * 128 + og * 4];
      const float4 wr = *(const float4*)&WresT[kk * 128 + og * 4];
      #pragma unroll
      for (int j = 0; j < 2; ++j) {
        const float u = Ul[(nr * 2 + j) * 128 + kk];
        const float xx = Xl[(nr * 2 + j) * 128 + kk];
        accn[j][0] = fmaf(u, wn.x, accn[j][0]);
        accn[j][1] = fmaf(u, wn.y, accn[j][1]);
        accn[j][2] = fmaf(u, wn.z, accn[j][2]);
        accn[j][3] = fmaf(u, wn.w, accn[j][3]);
        accr[j][0] = fmaf(xx, wr.x, accr[j][0]);
        accr[j][1] = fmaf(xx, wr.y, accr[j][1]);
        accr[j][2] = fmaf(xx, wr.z, accr[j][2]);
        accr[j][3] = fmaf(xx, wr.w, accr[j][3]);
      }
    }
    const float4 b = *(const float4*)&b_nn[og * 4];
    #pragma unroll
    for (int j = 0; j < 2; ++j) {
      const int n = tile * 16 + nr * 2 + j;
      if (n < N) {
        float4 o4;
        o4.x = (fmaxf(accn[j][0] + b.x, 0.f) + accr[j][0]) * INV_SQRT2;
        o4.y = (fmaxf(accn[j][1] + b.y, 0.f) + accr[j][1]) * INV_SQRT2;
        o4.z = (fmaxf(accn[j][2] + b.z, 0.f) + accr[j][2]) * INV_SQRT2;
        o4.w = (fmaxf(accn[j][3] + b.w, 0.f) + accr[j][3]) * INV_SQRT2;
        *(float4*)&out[(size_t)n * 128 + og * 4] = o4;
      }
    }
  }
}

// ---------- legacy fallback (round-1 path, atomics) ----------
__global__ __launch_bounds__(256) void edge_kernel_legacy(
    const float* __restrict__ x, const int* __restrict__ ei,
    const float* __restrict__ edge_attr, const float* __restrict__ W_edge,
    float* aggr, int E) {
  __shared__ float Wl[64 * 128];
  __shared__ float Al[32 * 64];
  const int tid = threadIdx.x;
  for (int idx = tid; idx < 128 * 64; idx += 256) {
    int o = idx >> 6, k = idx & 63;
    Wl[k * 128 + o] = W_edge[idx];
  }
  const int og = tid & 31;
  const int er = tid >> 5;
  const int ntiles = (E + 31) >> 5;
  for (int tile = blockIdx.x; tile < ntiles; tile += gridDim.x) {
    __syncthreads();
    {
      const float* src_ptr = edge_attr + (size_t)tile * 32 * 64;
      const int limit = E * 64 - tile * 32 * 64;
      for (int idx = tid; idx < 2048; idx += 256)
        Al[idx] = (idx < limit) ? src_ptr[idx] : 0.f;
    }
    __syncthreads();
    float acc[4][4] = {};
    #pragma unroll 4
    for (int k = 0; k < 64; ++k) {
      const float4 w = *(const float4*)&Wl[k * 128 + og * 4];
      #pragma unroll
      for (int j = 0; j < 4; ++j) {
        const float a = Al[(er * 4 + j) * 64 + k];
        acc[j][0] = fmaf(a, w.x, acc[j][0]);
        acc[j][1] = fmaf(a, w.y, acc[j][1]);
        acc[j][2] = fmaf(a, w.z, acc[j][2]);
        acc[j][3] = fmaf(a, w.w, acc[j][3]);
      }
    }
    #pragma unroll
    for (int j = 0; j < 4; ++j) {
      const int e = tile * 32 + er * 4 + j;
      if (e < E) {
        const int s = ei[e];
        const int d = ei[E + e];
        const float4 xv = *(const float4*)&x[(size_t)s * 128 + og * 4];
        float* ap = aggr + (size_t)d * 128 + og * 4;
        atomicAdd(ap + 0, fmaxf(xv.x + acc[j][0], 0.f));
        atomicAdd(ap + 1, fmaxf(xv.y + acc[j][1], 0.f));
        atomicAdd(ap + 2, fmaxf(xv.z + acc[j][2], 0.f));
        atomicAdd(ap + 3, fmaxf(xv.w + acc[j][3], 0.f));
      }
    }
  }
}

__global__ __launch_bounds__(256) void node_kernel_legacy(
    const float* __restrict__ x, const float* __restrict__ WT,
    const float* __restrict__ b_nn, float* io, int N) {
  __shared__ float Ul[16 * 128];
  __shared__ float Xl[16 * 128];
  const int tid = threadIdx.x;
  const int og = tid & 31;
  const int nr = tid >> 5;
  const float* WnnT = WT;
  const float* WresT = WT + 128 * 128;
  const int ntiles = (N + 15) >> 4;
  for (int tile = blockIdx.x; tile < ntiles; tile += gridDim.x) {
    __syncthreads();
    {
      const size_t base = (size_t)tile * 16 * 128;
      const int limit = N * 128 - (int)base;
      for (int idx = tid; idx < 2048; idx += 256) {
        const float xv = (idx < limit) ? x[base + idx] : 0.f;
        const float av = (idx < limit) ? io[base + idx] : 0.f;
        Xl[idx] = xv;
        Ul[idx] = fmaf(1.00001f, xv, av);
      }
    }
    __syncthreads();
    float accn[2][4] = {}, accr[2][4] = {};
    #pragma unroll 4
    for (int kk = 0; kk < 128; ++kk) {
      const float4 wn = *(const float4*)&WnnT[kk * 128 + og * 4];
      const float4 wr = *(const float4*)&WresT[kk * 128 + og * 4];
      #pragma unroll
      for (int j = 0; j < 2; ++j) {
        const float u = Ul[(nr * 2 + j) * 128 + kk];
        const float xx = Xl[(nr * 2 + j) * 128 + kk];
        accn[j][0] = fmaf(u, wn.x, accn[j][0]);
        accn[j][1] = fmaf(u, wn.y, accn[j][1]);
        accn[j][2] = fmaf(u, wn.z, accn[j][2]);
        accn[j][3] = fmaf(u, wn.w, accn[j][3]);
        accr[j][0] = fmaf(xx, wr.x, accr[j][0]);
        accr[j][1] = fmaf(xx, wr.y, accr[j][1]);
        accr[j][2] = fmaf(xx, wr.z, accr[j][2]);
        accr[j][3] = fmaf(xx, wr.w, accr[j][3]);
      }
    }
    const float4 b = *(const float4*)&b_nn[og * 4];
    #pragma unroll
    for (int j = 0; j < 2; ++j) {
      const int n = tile * 16 + nr * 2 + j;
      if (n < N) {
        float4 o4;
        o4.x = (fmaxf(accn[j][0] + b.x, 0.f) + accr[j][0]) * INV_SQRT2;
        o4.y = (fmaxf(accn[j][1] + b.y, 0.f) + accr[j][1]) * INV_SQRT2;
        o4.z = (fmaxf(accn[j][2] + b.z, 0.f) + accr[j][2]) * INV_SQRT2;
        o4.w = (fmaxf(accn[j][3] + b.w, 0.f) + accr[j][3]) * INV_SQRT2;
        *(float4*)&io[(size_t)n * 128 + og * 4] = o4;
      }
    }
  }
}

extern "C" void kernel_launch(void* const* d_in, const int* in_sizes, int n_in,
                              void* d_out, int out_size, void* d_ws, size_t ws_size,
                              hipStream_t stream) {
  const float* x      = (const float*)d_in[0];
  const int*   ei     = (const int*)d_in[1];
  const float* ea     = (const float*)d_in[2];
  const float* W_edge = (const float*)d_in[3];
  const float* W_nn   = (const float*)d_in[4];
  const float* b_nn   = (const float*)d_in[5];
  const float* W_res  = (const float*)d_in[6];
  float* out = (float*)d_out;
  const int N = in_sizes[0] / 128;
  const int E = in_sizes[2] / 64;

  char* ws = (char*)d_ws;
  // ws layout
  const size_t WT_OFF    = 0;                       // 2*128*128*4 = 131072 B
  const size_t CNT_OFF   = 131072;                  // N ints
  const size_t OFF_OFF   = CNT_OFF + (size_t)N * 4;
  const size_t CUR_OFF   = OFF_OFF + (size_t)N * 4;
  const size_t BSUM_OFF  = CUR_OFF + (size_t)N * 4;
  const size_t ORDER_OFF = (BSUM_OFF + 2048 + 255) & ~(size_t)255;  // E ints
  const size_t MSG_OFF   = (ORDER_OFF + (size_t)E * 4 + 255) & ~(size_t)255;
  const size_t NEED      = MSG_OFF + (size_t)E * 128 * 2;

  float* WT = (float*)(ws + WT_OFF);
  transpose_w_kernel<<<(128 * 128 + 255) / 256, 256, 0, stream>>>(W_nn, W_res, WT);

  if (ws_size >= NEED) {
    int* cnt   = (int*)(ws + CNT_OFF);
    int* off   = (int*)(ws + OFF_OFF);
    int* cur   = (int*)(ws + CUR_OFF);
    int* bsum  = (int*)(ws + BSUM_OFF);
    int* order = (int*)(ws + ORDER_OFF);
    unsigned short* msg = (unsigned short*)(ws + MSG_OFF);

    const int nb = (N + 255) / 256;   // 391 for N=100000 (fits single 512-scan)
    hipMemsetAsync(cnt, 0, (size_t)N * 4, stream);
    hist_kernel<<<(E + 255) / 256, 256, 0, stream>>>(ei, cnt, E);
    scan1_kernel<<<nb, 256, 0, stream>>>(cnt, off, bsum, N);
    scan2_kernel<<<1, 512, 0, stream>>>(bsum, nb);
    scan3_kernel<<<nb, 256, 0, stream>>>(off, cur, bsum, N);
    scatter_kernel<<<(E + 255) / 256, 256, 0, stream>>>(ei, cur, order, E);

    const int etiles = (E + 31) / 32;
    msg_kernel<<<(etiles < 4096 ? etiles : 4096), 256, 0, stream>>>(
        x, ei, ea, W_edge, msg, E);
    const int ntiles = (N + 15) / 16;
    node_gather_kernel<<<(ntiles < 2048 ? ntiles : 2048), 256, 0, stream>>>(
        x, WT, b_nn, off, cnt, order, msg, out, N);
  } else {
    // fallback: round-1 atomic path
    hipMemsetAsync(d_out, 0, (size_t)N * 128 * sizeof(float), stream);
    const int etiles = (E + 31) / 32;
    edge_kernel_legacy<<<(etiles < 4096 ? etiles : 4096), 256, 0, stream>>>(
        x, ei, ea, W_edge, out, E);
    const int ntiles = (N + 15) / 16;
    node_kernel_legacy<<<(ntiles < 2048 ? ntiles : 2048), 256, 0, stream>>>(
        x, WT, b_nn, out, N);
  }
}

// Round 3
// 471.408 us; speedup vs baseline: 2.2983x; 1.2870x over previous
//
#include <hip/hip_runtime.h>
#include <hip/hip_bf16.h>

#define INV_SQRT2 0.7071067811865475f

static __device__ __forceinline__ unsigned short f2bf(float f) {
  __hip_bfloat16 h = __float2bfloat16(f);
  return *(unsigned short*)&h;
}
static __device__ __forceinline__ float bf2f(unsigned short u) {
  unsigned int bits = ((unsigned int)u) << 16;
  return *(float*)&bits;
}

// ---------- weight transpose (k-major) ----------
__global__ __launch_bounds__(256) void transpose_w_kernel(
    const float* __restrict__ W_nn, const float* __restrict__ W_res,
    float* __restrict__ WT) {
  int idx = blockIdx.x * 256 + threadIdx.x;
  if (idx < 128 * 128) {
    int o = idx >> 7, k = idx & 127;
    WT[k * 128 + o] = W_nn[idx];
    WT[128 * 128 + k * 128 + o] = W_res[idx];
  }
}

// ---------- CSR build: histogram / scan / rank-scatter ----------
__global__ __launch_bounds__(256) void hist_kernel(const int* __restrict__ ei,
                                                   int* cnt, int E) {
  int e = blockIdx.x * 256 + threadIdx.x;
  if (e < E) atomicAdd(&cnt[ei[E + e]], 1);
}

__global__ __launch_bounds__(256) void scan1_kernel(const int* __restrict__ cnt,
                                                    int* off, int* bsum, int N) {
  __shared__ int s[256];
  const int tid = threadIdx.x;
  const int gid = blockIdx.x * 256 + tid;
  const int v = (gid < N) ? cnt[gid] : 0;
  s[tid] = v;
  for (int o = 1; o < 256; o <<= 1) {
    __syncthreads();
    int t = (tid >= o) ? s[tid - o] : 0;
    __syncthreads();
    s[tid] += t;
  }
  if (gid < N) off[gid] = s[tid] - v;
  if (tid == 255) bsum[blockIdx.x] = s[255];
}

__global__ __launch_bounds__(512) void scan2_kernel(int* bsum, int nb) {
  __shared__ int s[512];
  const int tid = threadIdx.x;
  const int v = (tid < nb) ? bsum[tid] : 0;
  s[tid] = v;
  for (int o = 1; o < 512; o <<= 1) {
    __syncthreads();
    int t = (tid >= o) ? s[tid - o] : 0;
    __syncthreads();
    s[tid] += t;
  }
  if (tid < nb) bsum[tid] = s[tid] - v;
}

__global__ __launch_bounds__(256) void scan3_kernel(int* off, int* cur,
                                                    const int* __restrict__ bsum,
                                                    int N) {
  int gid = blockIdx.x * 256 + threadIdx.x;
  if (gid < N) {
    int v = off[gid] + bsum[blockIdx.x];
    off[gid] = v;
    cur[gid] = v;
  }
}

// rank[e] = CSR position of edge e (inverse permutation).
__global__ __launch_bounds__(256) void rank_kernel(const int* __restrict__ ei,
                                                   int* cur, int* rank, int E) {
  int e = blockIdx.x * 256 + threadIdx.x;
  if (e < E) rank[e] = atomicAdd(&cur[ei[E + e]], 1);
}

// ---------- phase 2a: per-edge message, written to CSR slot as bf16 ----------
// msg[rank[e]][:] = relu(x[src[e]] + W_edge @ attr[e])
__global__ __launch_bounds__(256) void msg_kernel(
    const float* __restrict__ x, const int* __restrict__ ei,
    const int* __restrict__ rank,
    const float* __restrict__ edge_attr, const float* __restrict__ W_edge,
    unsigned short* __restrict__ msg, int E) {
  __shared__ float Wl[64 * 128];   // k-major: Wl[k][o]
  __shared__ float Al[32 * 64];    // attr tile [e][k]
  const int tid = threadIdx.x;
  for (int idx = tid; idx < 128 * 64; idx += 256) {
    int o = idx >> 6, k = idx & 63;
    Wl[k * 128 + o] = W_edge[idx];
  }
  const int og = tid & 31;
  const int er = tid >> 5;
  const int ntiles = (E + 31) >> 5;
  for (int tile = blockIdx.x; tile < ntiles; tile += gridDim.x) {
    __syncthreads();
    {
      const float* src_ptr = edge_attr + (size_t)tile * 32 * 64;
      const int limit = E * 64 - tile * 32 * 64;
      for (int idx = tid; idx < 2048; idx += 256)
        Al[idx] = (idx < limit) ? src_ptr[idx] : 0.f;
    }
    __syncthreads();
    float4 acc[4];
    #pragma unroll
    for (int j = 0; j < 4; ++j) acc[j] = make_float4(0.f, 0.f, 0.f, 0.f);
    #pragma unroll 4
    for (int kk = 0; kk < 64; kk += 4) {
      const float4 w0 = *(const float4*)&Wl[(kk + 0) * 128 + og * 4];
      const float4 w1 = *(const float4*)&Wl[(kk + 1) * 128 + og * 4];
      const float4 w2 = *(const float4*)&Wl[(kk + 2) * 128 + og * 4];
      const float4 w3 = *(const float4*)&Wl[(kk + 3) * 128 + og * 4];
      #pragma unroll
      for (int j = 0; j < 4; ++j) {
        const float4 a = *(const float4*)&Al[(er * 4 + j) * 64 + kk];
        acc[j].x = fmaf(a.x, w0.x, fmaf(a.y, w1.x, fmaf(a.z, w2.x, fmaf(a.w, w3.x, acc[j].x))));
        acc[j].y = fmaf(a.x, w0.y, fmaf(a.y, w1.y, fmaf(a.z, w2.y, fmaf(a.w, w3.y, acc[j].y))));
        acc[j].z = fmaf(a.x, w0.z, fmaf(a.y, w1.z, fmaf(a.z, w2.z, fmaf(a.w, w3.z, acc[j].z))));
        acc[j].w = fmaf(a.x, w0.w, fmaf(a.y, w1.w, fmaf(a.z, w2.w, fmaf(a.w, w3.w, acc[j].w))));
      }
    }
    #pragma unroll
    for (int j = 0; j < 4; ++j) {
      const int e = tile * 32 + er * 4 + j;
      if (e < E) {
        const int s = ei[e];
        const int p = rank[e];
        const float4 xv = *(const float4*)&x[(size_t)s * 128 + og * 4];
        ushort4 pk;
        pk.x = f2bf(fmaxf(xv.x + acc[j].x, 0.f));
        pk.y = f2bf(fmaxf(xv.y + acc[j].y, 0.f));
        pk.z = f2bf(fmaxf(xv.z + acc[j].z, 0.f));
        pk.w = f2bf(fmaxf(xv.w + acc[j].w, 0.f));
        *(ushort4*)&msg[(size_t)p * 128 + og * 4] = pk;
      }
    }
  }
}

// ---------- phase 2b: sequential CSR segment-sum + fused node GEMMs ----------
// Tile = 32 nodes. msg rows for a node are contiguous: pure streaming reads.
__global__ __launch_bounds__(256) void node_gather_kernel(
    const float* __restrict__ x, const float* __restrict__ WT,
    const float* __restrict__ b_nn, const int* __restrict__ off,
    const int* __restrict__ cnt,
    const unsigned short* __restrict__ msg, float* __restrict__ out, int N) {
  __shared__ float Ul[32 * 128];
  __shared__ float Xl[32 * 128];
  const int tid = threadIdx.x;
  const int k = tid & 127;       // channel for the staging phase
  const int half = tid >> 7;     // 0/1
  const int og = tid & 31;
  const int nr = tid >> 5;       // 0..7 -> 4 nodes each
  const float* WnnT = WT;
  const float* WresT = WT + 128 * 128;
  const int ntiles = (N + 31) >> 5;
  for (int tile = blockIdx.x; tile < ntiles; tile += gridDim.x) {
    __syncthreads();
    for (int j = half; j < 32; j += 2) {
      const int n = tile * 32 + j;
      float xv = 0.f, sum = 0.f;
      if (n < N) {
        xv = x[(size_t)n * 128 + k];
        const int o = off[n];
        const int c = cnt[n];
        const unsigned short* p = msg + (size_t)o * 128 + k;
        float s0 = 0.f, s1 = 0.f, s2 = 0.f, s3 = 0.f;
        int t = 0;
        for (; t + 4 <= c; t += 4) {
          s0 += bf2f(p[0]);
          s1 += bf2f(p[128]);
          s2 += bf2f(p[256]);
          s3 += bf2f(p[384]);
          p += 512;
        }
        for (; t < c; ++t) { s0 += bf2f(p[0]); p += 128; }
        sum = (s0 + s1) + (s2 + s3);
      }
      Xl[j * 128 + k] = xv;
      Ul[j * 128 + k] = fmaf(1.00001f, xv, sum);
    }
    __syncthreads();
    float4 accn[4], accr[4];
    #pragma unroll
    for (int j = 0; j < 4; ++j) {
      accn[j] = make_float4(0.f, 0.f, 0.f, 0.f);
      accr[j] = make_float4(0.f, 0.f, 0.f, 0.f);
    }
    #pragma unroll 2
    for (int kk = 0; kk < 128; kk += 4) {
      const float4 wn0 = *(const float4*)&WnnT[(kk + 0) * 128 + og * 4];
      const float4 wn1 = *(const float4*)&WnnT[(kk + 1) * 128 + og * 4];
      const float4 wn2 = *(const float4*)&WnnT[(kk + 2) * 128 + og * 4];
      const float4 wn3 = *(const float4*)&WnnT[(kk + 3) * 128 + og * 4];
      const float4 wr0 = *(const float4*)&WresT[(kk + 0) * 128 + og * 4];
      const float4 wr1 = *(const float4*)&WresT[(kk + 1) * 128 + og * 4];
      const float4 wr2 = *(const float4*)&WresT[(kk + 2) * 128 + og * 4];
      const float4 wr3 = *(const float4*)&WresT[(kk + 3) * 128 + og * 4];
      #pragma unroll
      for (int j = 0; j < 4; ++j) {
        const int row = (nr * 4 + j) * 128;
        const float4 u = *(const float4*)&Ul[row + kk];
        const float4 xx = *(const float4*)&Xl[row + kk];
        accn[j].x = fmaf(u.x, wn0.x, fmaf(u.y, wn1.x, fmaf(u.z, wn2.x, fmaf(u.w, wn3.x, accn[j].x))));
        accn[j].y = fmaf(u.x, wn0.y, fmaf(u.y, wn1.y, fmaf(u.z, wn2.y, fmaf(u.w, wn3.y, accn[j].y))));
        accn[j].z = fmaf(u.x, wn0.z, fmaf(u.y, wn1.z, fmaf(u.z, wn2.z, fmaf(u.w, wn3.z, accn[j].z))));
        accn[j].w = fmaf(u.x, wn0.w, fmaf(u.y, wn1.w, fmaf(u.z, wn2.w, fmaf(u.w, wn3.w, accn[j].w))));
        accr[j].x = fmaf(xx.x, wr0.x, fmaf(xx.y, wr1.x, fmaf(xx.z, wr2.x, fmaf(xx.w, wr3.x, accr[j].x))));
        accr[j].y = fmaf(xx.x, wr0.y, fmaf(xx.y, wr1.y, fmaf(xx.z, wr2.y, fmaf(xx.w, wr3.y, accr[j].y))));
        accr[j].z = fmaf(xx.x, wr0.z, fmaf(xx.y, wr1.z, fmaf(xx.z, wr2.z, fmaf(xx.w, wr3.z, accr[j].z))));
        accr[j].w = fmaf(xx.x, wr0.w, fmaf(xx.y, wr1.w, fmaf(xx.z, wr2.w, fmaf(xx.w, wr3.w, accr[j].w))));
      }
    }
    const float4 b = *(const float4*)&b_nn[og * 4];
    #pragma unroll
    for (int j = 0; j < 4; ++j) {
      const int n = tile * 32 + nr * 4 + j;
      if (n < N) {
        float4 o4;
        o4.x = (fmaxf(accn[j].x + b.x, 0.f) + accr[j].x) * INV_SQRT2;
        o4.y = (fmaxf(accn[j].y + b.y, 0.f) + accr[j].y) * INV_SQRT2;
        o4.z = (fmaxf(accn[j].z + b.z, 0.f) + accr[j].z) * INV_SQRT2;
        o4.w = (fmaxf(accn[j].w + b.w, 0.f) + accr[j].w) * INV_SQRT2;
        *(float4*)&out[(size_t)n * 128 + og * 4] = o4;
      }
    }
  }
}

// ---------- legacy fallback (round-1 path, atomics) ----------
__global__ __launch_bounds__(256) void edge_kernel_legacy(
    const float* __restrict__ x, const int* __restrict__ ei,
    const float* __restrict__ edge_attr, const float* __restrict__ W_edge,
    float* aggr, int E) {
  __shared__ float Wl[64 * 128];
  __shared__ float Al[32 * 64];
  const int tid = threadIdx.x;
  for (int idx = tid; idx < 128 * 64; idx += 256) {
    int o = idx >> 6, k = idx & 63;
    Wl[k * 128 + o] = W_edge[idx];
  }
  const int og = tid & 31;
  const int er = tid >> 5;
  const int ntiles = (E + 31) >> 5;
  for (int tile = blockIdx.x; tile < ntiles; tile += gridDim.x) {
    __syncthreads();
    {
      const float* src_ptr = edge_attr + (size_t)tile * 32 * 64;
      const int limit = E * 64 - tile * 32 * 64;
      for (int idx = tid; idx < 2048; idx += 256)
        Al[idx] = (idx < limit) ? src_ptr[idx] : 0.f;
    }
    __syncthreads();
    float acc[4][4] = {};
    #pragma unroll 4
    for (int k = 0; k < 64; ++k) {
      const float4 w = *(const float4*)&Wl[k * 128 + og * 4];
      #pragma unroll
      for (int j = 0; j < 4; ++j) {
        const float a = Al[(er * 4 + j) * 64 + k];
        acc[j][0] = fmaf(a, w.x, acc[j][0]);
        acc[j][1] = fmaf(a, w.y, acc[j][1]);
        acc[j][2] = fmaf(a, w.z, acc[j][2]);
        acc[j][3] = fmaf(a, w.w, acc[j][3]);
      }
    }
    #pragma unroll
    for (int j = 0; j < 4; ++j) {
      const int e = tile * 32 + er * 4 + j;
      if (e < E) {
        const int s = ei[e];
        const int d = ei[E + e];
        const float4 xv = *(const float4*)&x[(size_t)s * 128 + og * 4];
        float* ap = aggr + (size_t)d * 128 + og * 4;
        atomicAdd(ap + 0, fmaxf(xv.x + acc[j][0], 0.f));
        atomicAdd(ap + 1, fmaxf(xv.y + acc[j][1], 0.f));
        atomicAdd(ap + 2, fmaxf(xv.z + acc[j][2], 0.f));
        atomicAdd(ap + 3, fmaxf(xv.w + acc[j][3], 0.f));
      }
    }
  }
}

__global__ __launch_bounds__(256) void node_kernel_legacy(
    const float* __restrict__ x, const float* __restrict__ WT,
    const float* __restrict__ b_nn, float* io, int N) {
  __shared__ float Ul[16 * 128];
  __shared__ float Xl[16 * 128];
  const int tid = threadIdx.x;
  const int og = tid & 31;
  const int nr = tid >> 5;
  const float* WnnT = WT;
  const float* WresT = WT + 128 * 128;
  const int ntiles = (N + 15) >> 4;
  for (int tile = blockIdx.x; tile < ntiles; tile += gridDim.x) {
    __syncthreads();
    {
      const size_t base = (size_t)tile * 16 * 128;
      const int limit = N * 128 - (int)base;
      for (int idx = tid; idx < 2048; idx += 256) {
        const float xv = (idx < limit) ? x[base + idx] : 0.f;
        const float av = (idx < limit) ? io[base + idx] : 0.f;
        Xl[idx] = xv;
        Ul[idx] = fmaf(1.00001f, xv, av);
      }
    }
    __syncthreads();
    float accn[2][4] = {}, accr[2][4] = {};
    #pragma unroll 4
    for (int kk = 0; kk < 128; ++kk) {
      const float4 wn = *(const float4*)&WnnT[kk * 128 + og * 4];
      const float4 wr = *(const float4*)&WresT[kk * 128 + og * 4];
      #pragma unroll
      for (int j = 0; j < 2; ++j) {
        const float u = Ul[(nr * 2 + j) * 128 + kk];
        const float xx = Xl[(nr * 2 + j) * 128 + kk];
        accn[j][0] = fmaf(u, wn.x, accn[j][0]);
        accn[j][1] = fmaf(u, wn.y, accn[j][1]);
        accn[j][2] = fmaf(u, wn.z, accn[j][2]);
        accn[j][3] = fmaf(u, wn.w, accn[j][3]);
        accr[j][0] = fmaf(xx, wr.x, accr[j][0]);
        accr[j][1] = fmaf(xx, wr.y, accr[j][1]);
        accr[j][2] = fmaf(xx, wr.z, accr[j][2]);
        accr[j][3] = fmaf(xx, wr.w, accr[j][3]);
      }
    }
    const float4 b = *(const float4*)&b_nn[og * 4];
    #pragma unroll
    for (int j = 0; j < 2; ++j) {
      const int n = tile * 16 + nr * 2 + j;
      if (n < N) {
        float4 o4;
        o4.x = (fmaxf(accn[j][0] + b.x, 0.f) + accr[j][0]) * INV_SQRT2;
        o4.y = (fmaxf(accn[j][1] + b.y, 0.f) + accr[j][1]) * INV_SQRT2;
        o4.z = (fmaxf(accn[j][2] + b.z, 0.f) + accr[j][2]) * INV_SQRT2;
        o4.w = (fmaxf(accn[j][3] + b.w, 0.f) + accr[j][3]) * INV_SQRT2;
        *(float4*)&io[(size_t)n * 128 + og * 4] = o4;
      }
    }
  }
}

extern "C" void kernel_launch(void* const* d_in, const int* in_sizes, int n_in,
                              void* d_out, int out_size, void* d_ws, size_t ws_size,
                              hipStream_t stream) {
  const float* x      = (const float*)d_in[0];
  const int*   ei     = (const int*)d_in[1];
  const float* ea     = (const float*)d_in[2];
  const float* W_edge = (const float*)d_in[3];
  const float* W_nn   = (const float*)d_in[4];
  const float* b_nn   = (const float*)d_in[5];
  const float* W_res  = (const float*)d_in[6];
  float* out = (float*)d_out;
  const int N = in_sizes[0] / 128;
  const int E = in_sizes[2] / 64;

  char* ws = (char*)d_ws;
  const size_t WT_OFF    = 0;                       // 131072 B
  const size_t CNT_OFF   = 131072;                  // N ints
  const size_t OFF_OFF   = CNT_OFF + (size_t)N * 4;
  const size_t CUR_OFF   = OFF_OFF + (size_t)N * 4;
  const size_t BSUM_OFF  = CUR_OFF + (size_t)N * 4;
  const size_t RANK_OFF  = (BSUM_OFF + 2048 + 255) & ~(size_t)255;  // E ints
  const size_t MSG_OFF   = (RANK_OFF + (size_t)E * 4 + 255) & ~(size_t)255;
  const size_t NEED      = MSG_OFF + (size_t)E * 128 * 2;

  float* WT = (float*)(ws + WT_OFF);
  transpose_w_kernel<<<(128 * 128 + 255) / 256, 256, 0, stream>>>(W_nn, W_res, WT);

  if (ws_size >= NEED) {
    int* cnt   = (int*)(ws + CNT_OFF);
    int* off   = (int*)(ws + OFF_OFF);
    int* cur   = (int*)(ws + CUR_OFF);
    int* bsum  = (int*)(ws + BSUM_OFF);
    int* rank  = (int*)(ws + RANK_OFF);
    unsigned short* msg = (unsigned short*)(ws + MSG_OFF);

    const int nb = (N + 255) / 256;   // <= 512 for N <= 131072
    hipMemsetAsync(cnt, 0, (size_t)N * 4, stream);
    hist_kernel<<<(E + 255) / 256, 256, 0, stream>>>(ei, cnt, E);
    scan1_kernel<<<nb, 256, 0, stream>>>(cnt, off, bsum, N);
    scan2_kernel<<<1, 512, 0, stream>>>(bsum, nb);
    scan3_kernel<<<nb, 256, 0, stream>>>(off, cur, bsum, N);
    rank_kernel<<<(E + 255) / 256, 256, 0, stream>>>(ei, cur, rank, E);

    const int etiles = (E + 31) / 32;
    msg_kernel<<<(etiles < 4096 ? etiles : 4096), 256, 0, stream>>>(
        x, ei, rank, ea, W_edge, msg, E);
    const int ntiles = (N + 31) / 32;
    node_gather_kernel<<<ntiles, 256, 0, stream>>>(
        x, WT, b_nn, off, cnt, msg, out, N);
  } else {
    hipMemsetAsync(d_out, 0, (size_t)N * 128 * sizeof(float), stream);
    const int etiles = (E + 31) / 32;
    edge_kernel_legacy<<<(etiles < 4096 ? etiles : 4096), 256, 0, stream>>>(
        x, ei, ea, W_edge, out, E);
    const int ntiles = (N + 15) / 16;
    node_kernel_legacy<<<(ntiles < 2048 ? ntiles : 2048), 256, 0, stream>>>(
        x, WT, b_nn, out, N);
  }
}